// Round 12
// baseline (299.196 us; speedup 1.0000x reference)
//
#include <hip/hip_runtime.h>
#include <math.h>

// Fused separable-Gaussian SSIM. N=32,C=3,H=W=512 fp32.
// Windows (5,11),(11,5),(11,11), sigma=1.5, zero padding.
// u/v reformulation (u=x+y, v=x-y) + packed fp32 (v_pk_fma_f32 via v2).
// LDS layout: per (sub, pair-channel) row of 70 x 16B chunks, with a
// 16B-chunk XOR swizzle phys(c) = c ^ ((c>>3)&7) applied consistently on
// write (v2 granularity) and read (float4 granularity). This spreads the
// H-phase b128 reads (lane stride 32B -> 16-bank 8-way alias, 2x LDS cost)
// across all 32 banks (optimal 8 cyc/wave-read). Raw conv sums throughout;
// normalizer folded exactly into SSIM coefficients (k1=.5*s^2, k2=.5*s).
//   A(5,11)=H11(inner)  B(11,5)=H5(full)  C(11,11)=H11(full)

#define H 512
#define W 512
#define NPLANE 96
#define TW 128          // output cols per block
#define PW 138          // TW + 10 halo cols
#define NCHUNK 70       // 16B chunks per channel row (140 v2)
#define ROWB (NCHUNK * 16)       // 1120 B per pair-channel row
#define SUBB (4 * ROWB)          // 4480 B per sub-row
#define BAND 128        // output rows per block
#define R 8             // rows per barrier iteration
#define NITER (BAND / R)
#define NTHREADS 256    // 4 waves; H phase has exactly 256 slots

typedef float v2 __attribute__((ext_vector_type(2)));

struct GaussW {
  float e[11];                  // raw exp(-d^2/4.5) weights
  float k2A, k1A, k2C, k1C;     // .5*s, .5*s^2 for combos A/B and C
};

__device__ __forceinline__ int swzchunk(int c) { return c ^ ((c >> 3) & 7); }

// m = raw (mu_u, mu_v), s = raw (Muu, Mvv); k2=.5*scale, k1=.5*scale^2
__device__ __forceinline__ float ssim_uv(v2 m, v2 s, float k2, float k1) {
  const float C1 = 0.0001f;   // 0.01^2
  const float C2 = 0.0009f;   // 0.03^2
  v2 PQ = m * m;                       // v_pk_mul_f32
  float t1 = PQ.x - PQ.y, t2 = PQ.x + PQ.y;
  float n1 = fmaf(k1, t1, C1);
  float d1 = fmaf(k1, t2, C1);
  float u1 = s.x - s.y, u2 = s.x + s.y;
  float n2 = fmaf(k2, u1, fmaf(-k1, t1, C2));
  float d2 = fmaf(k2, u2, fmaf(-k1, t2, C2));
  return (n1 * n2) * __builtin_amdgcn_rcpf(d1 * d2);  // den >= C1*C2 > 0
}

__global__ __launch_bounds__(NTHREADS, 4) void ssim_kernel(
    const float* __restrict__ img1, const float* __restrict__ img2,
    double* __restrict__ acc, GaussW w) {
  // pair-channels: 0 = inner(u,v), 1 = inner(uu,vv), 2 = full(u,v), 3 = full(uu,vv)
  __shared__ __align__(16) char sB[R * SUBB];     // 35,840 B -> 4 blocks/CU
  __shared__ double red[NTHREADS / 64];

  const int t = threadIdx.x;
  const int tile = blockIdx.x, band = blockIdx.y, plane = blockIdx.z;
  const float* p1 = img1 + (size_t)plane * H * W;
  const float* p2 = img2 + (size_t)plane * H * W;
  const int c0 = tile * TW;
  const int r0 = band * BAND;
  const int col = c0 + t - 5;            // column owned in V phase
  const bool vact = (t < PW);
  const bool colok = vact && ((unsigned)col < (unsigned)W);

  // swizzled intra-row byte offsets (constant per thread)
  const int wOff = (swzchunk(t >> 1) << 4) + ((t & 1) << 3);   // v2 write
  int rdOff[7];                                                // float4 reads
#pragma unroll
  for (int q = 0; q < 7; ++q) rdOff[q] = swzchunk(2 * (t & 31) + q) << 4;

  // rolling windows: slot k = row (r-5+k) for current output row r
  v2 wUV[11], wQ[11];
#pragma unroll
  for (int k = 0; k < 10; ++k) {
    int rr = r0 - 5 + k;
    bool ok = colok && (rr >= 0);
    float x = ok ? p1[rr * W + col] : 0.0f;
    float y = ok ? p2[rr * W + col] : 0.0f;
    v2 uv; uv.x = x + y; uv.y = x - y;
    wUV[k] = uv; wQ[k] = uv * uv;
  }

  double accT = 0.0;
  for (int it = 0; it < NITER; ++it) {
    const int rbase = r0 + it * R;
    // ---- V phase: each column-thread produces R rows x 4 pair-channels
    if (vact) {
      float nx[R], ny[R];
#pragma unroll
      for (int sub = 0; sub < R; ++sub) {          // batch loads up-front
        const int rr = rbase + sub + 5;
        bool ok = colok && (rr < H);
        nx[sub] = ok ? p1[rr * W + col] : 0.0f;
        ny[sub] = ok ? p2[rr * W + col] : 0.0f;
      }
#pragma unroll
      for (int sub = 0; sub < R; ++sub) {
        v2 uv; uv.x = nx[sub] + ny[sub]; uv.y = nx[sub] - ny[sub];
        wUV[10] = uv; wQ[10] = uv * uv;
        v2 iUV = {0, 0}, iQ = {0, 0}, oUV = {0, 0}, oQ = {0, 0};
#pragma unroll
        for (int k = 0; k < 11; ++k) {
          v2 ek = {w.e[k], w.e[k]};
          if (k >= 3 && k <= 7) {
            iUV = __builtin_elementwise_fma(ek, wUV[k], iUV);
            iQ  = __builtin_elementwise_fma(ek, wQ[k], iQ);
          } else {
            oUV = __builtin_elementwise_fma(ek, wUV[k], oUV);
            oQ  = __builtin_elementwise_fma(ek, wQ[k], oQ);
          }
        }
        char* wp = sB + sub * SUBB + wOff;
        *(v2*)(wp + 0 * ROWB) = iUV;
        *(v2*)(wp + 1 * ROWB) = iQ;
        *(v2*)(wp + 2 * ROWB) = iUV + oUV;
        *(v2*)(wp + 3 * ROWB) = iQ + oQ;
#pragma unroll
        for (int k = 0; k < 10; ++k) {             // shift (renamed by unroll)
          wUV[k] = wUV[k + 1]; wQ[k] = wQ[k + 1];
        }
      }
    }
    __syncthreads();

    // ---- H phase: 256 slots (R rows x 32 groups x 4 cols), 1 per thread
    {
      const int sub = t >> 5;
      const char* rbase_p = sB + sub * SUBB;
      float iterSum = 0.0f;

      v2 fUV[14], fQ[14];
      // Combo A: 11-tap conv over inner pair-channels, SSIM with A constants
      {
#pragma unroll
        for (int pc = 0; pc < 2; ++pc) {
          const char* rp = rbase_p + pc * ROWB;
          v2* dst = pc ? fQ : fUV;
#pragma unroll
          for (int q = 0; q < 7; ++q) {
            float4 r4 = *(const float4*)(rp + rdOff[q]);
            v2 lo; lo.x = r4.x; lo.y = r4.y;
            v2 hi; hi.x = r4.z; hi.y = r4.w;
            dst[2 * q] = lo; dst[2 * q + 1] = hi;
          }
        }
#pragma unroll
        for (int k = 0; k < 4; ++k) {
          v2 aUV = {0, 0}, aQ = {0, 0};
#pragma unroll
          for (int j = 0; j < 11; ++j) {
            v2 ej = {w.e[j], w.e[j]};
            aUV = __builtin_elementwise_fma(ej, fUV[k + j], aUV);
            aQ  = __builtin_elementwise_fma(ej, fQ[k + j], aQ);
          }
          iterSum += ssim_uv(aUV, aQ, w.k2A, w.k1A);
        }
      }
      // Combos C (full 11) and B (inner 5) share inner/outer over full chans
      {
#pragma unroll
        for (int pc = 0; pc < 2; ++pc) {
          const char* rp = rbase_p + (2 + pc) * ROWB;
          v2* dst = pc ? fQ : fUV;
#pragma unroll
          for (int q = 0; q < 7; ++q) {
            float4 r4 = *(const float4*)(rp + rdOff[q]);
            v2 lo; lo.x = r4.x; lo.y = r4.y;
            v2 hi; hi.x = r4.z; hi.y = r4.w;
            dst[2 * q] = lo; dst[2 * q + 1] = hi;
          }
        }
#pragma unroll
        for (int k = 0; k < 4; ++k) {
          v2 biUV = {0, 0}, biQ = {0, 0}, boUV = {0, 0}, boQ = {0, 0};
#pragma unroll
          for (int j = 0; j < 11; ++j) {
            v2 ej = {w.e[j], w.e[j]};
            if (j >= 3 && j <= 7) {
              biUV = __builtin_elementwise_fma(ej, fUV[k + j], biUV);
              biQ  = __builtin_elementwise_fma(ej, fQ[k + j], biQ);
            } else {
              boUV = __builtin_elementwise_fma(ej, fUV[k + j], boUV);
              boQ  = __builtin_elementwise_fma(ej, fQ[k + j], boQ);
            }
          }
          iterSum += ssim_uv(biUV + boUV, biQ + boQ, w.k2C, w.k1C);
          iterSum += ssim_uv(biUV, biQ, w.k2A, w.k1A);
        }
      }
      accT += (double)iterSum;
    }
    __syncthreads();
  }

  // block reduction (4 waves) -> one device atomic per block
#pragma unroll
  for (int off = 32; off > 0; off >>= 1) accT += __shfl_down(accT, off);
  const int wid = t >> 6;
  if ((t & 63) == 0) red[wid] = accT;
  __syncthreads();
  if (t == 0) {
    double s = 0.0;
    for (int k = 0; k < NTHREADS / 64; ++k) s += red[k];
    atomicAdd(acc, s);
  }
}

__global__ void finalize_kernel(const double* __restrict__ acc,
                                float* __restrict__ out) {
  out[0] = (float)(acc[0] * (1.0 / (3.0 * (double)NPLANE * H * W)));
}

extern "C" void kernel_launch(void* const* d_in, const int* in_sizes, int n_in,
                              void* d_out, int out_size, void* d_ws,
                              size_t ws_size, hipStream_t stream) {
  const float* img1 = (const float*)d_in[0];
  const float* img2 = (const float*)d_in[1];
  float* out = (float*)d_out;
  double* acc = (double*)d_ws;

  hipMemsetAsync(acc, 0, sizeof(double), stream);

  GaussW w;
  {
    double e64[11], S11 = 0.0, S5 = 0.0;
    for (int i = 0; i < 11; ++i) {
      double d = (double)(i - 5);
      e64[i] = exp(-d * d / 4.5);   // 2*sigma^2 = 4.5
      S11 += e64[i];
      if (i >= 3 && i <= 7) S5 += e64[i];
    }
    for (int i = 0; i < 11; ++i) w.e[i] = (float)e64[i];
    double sA = 1.0 / (S5 * S11);    // combos A and B
    double sC = 1.0 / (S11 * S11);   // combo C
    w.k2A = (float)(0.5 * sA);
    w.k1A = (float)(0.5 * sA * sA);
    w.k2C = (float)(0.5 * sC);
    w.k1C = (float)(0.5 * sC * sC);
  }

  dim3 grid(W / TW, H / BAND, NPLANE);   // 4 x 4 x 96 = 1536 blocks (4/CU)
  ssim_kernel<<<grid, NTHREADS, 0, stream>>>(img1, img2, acc, w);
  finalize_kernel<<<1, 1, 0, stream>>>(acc, out);
}